// Round 8
// baseline (306.392 us; speedup 1.0000x reference)
//
#include <hip/hip_runtime.h>

typedef __attribute__((ext_vector_type(8))) short bf16x8;
typedef __attribute__((ext_vector_type(4))) float f32x4;

__device__ __forceinline__ unsigned f2bf(float f) {
    union { float f; unsigned u; } v; v.f = f;
    return (v.u + 0x7FFFu + ((v.u >> 16) & 1u)) >> 16;
}

// prep: W' = gamma*Wh + I, stored bf16 TRANSPOSED and XOR-preswizzled:
// element (n,k) -> ws[n*256 + (k ^ ((n&7)<<3))]   (byte swizzle ((n&7)<<4))
__global__ void prep_w(const float* __restrict__ Wh, const float* __restrict__ gamma,
                       ushort* __restrict__ wsW) {
    int k = blockIdx.x, n = threadIdx.x;
    float v = gamma[0] * Wh[k * 256 + n] + (k == n ? 1.0f : 0.0f);
    wsW[n * 256 + (k ^ ((n & 7) << 3))] = (ushort)f2bf(v);
}

#define NBLK  256
#define ITERS 4
// rows: 256 blocks * 4 iters * 128 rows = 131072

// out = x @ W' + b'.  Persistent blocks: W' lives in LDS for the whole kernel;
// each wave owns 16 rows x 256 cols per iteration; x read exactly once.
__global__ __launch_bounds__(512, 2) void ccsa_gemm(
    const float* __restrict__ x, const ushort* __restrict__ wsW,
    const float* __restrict__ bh, const float* __restrict__ gamma,
    float* __restrict__ out)
{
    __shared__ char lds[131072 + 1024];   // W' bf16 swz + b' f32
    const int tid  = threadIdx.x;
    const int lane = tid & 63;
    const int wv   = tid >> 6;
    const int r15  = lane & 15;
    const int g    = lane >> 4;
    const int swz  = (r15 & 7) << 4;

    // ---- stage W' (pre-swizzled -> linear copy) + b' ----
#pragma unroll
    for (int i = 0; i < 16; ++i) {
        int c = i * 512 + tid;                       // 16B chunk id, 8192 total
        uint4 v = *(const uint4*)((const char*)wsW + c * 16);
        *(uint4*)(lds + c * 16) = v;
    }
    if (tid < 256) ((float*)(lds + 131072))[tid] = gamma[0] * bh[tid];

    // ---- prologue: issue A loads for iter 0 (fly during staging) ----
    const float* ap0 = x + ((long)blockIdx.x * 128 + wv * 16 + r15) * 256 + g * 8;
    float4 ld[16];
#pragma unroll
    for (int i = 0; i < 8; ++i) {
        ld[2*i]   = *(const float4*)(ap0 + i * 32);
        ld[2*i+1] = *(const float4*)(ap0 + i * 32 + 4);
    }
    __syncthreads();

    for (int j = 0; j < ITERS; ++j) {
        // convert current A tile to bf16 fragments
        bf16x8 af[8];
#pragma unroll
        for (int i = 0; i < 8; ++i) {
            union { uint4 u; bf16x8 h; } cv;
            cv.u.x = f2bf(ld[2*i].x)   | (f2bf(ld[2*i].y)   << 16);
            cv.u.y = f2bf(ld[2*i].z)   | (f2bf(ld[2*i].w)   << 16);
            cv.u.z = f2bf(ld[2*i+1].x) | (f2bf(ld[2*i+1].y) << 16);
            cv.u.w = f2bf(ld[2*i+1].z) | (f2bf(ld[2*i+1].w) << 16);
            af[i] = cv.h;
        }
        // prefetch next iteration's A (covered by K-loop + epilogue)
        if (j < ITERS - 1) {
            const float* ap = ap0 + (long)(j + 1) * (NBLK * 128 * 256);
#pragma unroll
            for (int i = 0; i < 8; ++i) {
                ld[2*i]   = *(const float4*)(ap + i * 32);
                ld[2*i+1] = *(const float4*)(ap + i * 32 + 4);
            }
        }

        // K-loop: 8 ksl x 16 n-tiles; B from LDS (conflict-free b128)
        f32x4 acc[16];
#pragma unroll
        for (int ni = 0; ni < 16; ++ni) acc[ni] = (f32x4){0.f, 0.f, 0.f, 0.f};
#pragma unroll
        for (int ksl = 0; ksl < 8; ++ksl) {
            const int ko = (ksl * 64 + g * 16) ^ swz;
#pragma unroll
            for (int ni = 0; ni < 16; ++ni) {
                bf16x8 bc = *(const bf16x8*)(lds + (ni * 16 + r15) * 512 + ko);
                acc[ni] = __builtin_amdgcn_mfma_f32_16x16x32_bf16(
                    bc, af[ksl], acc[ni], 0, 0, 0);
            }
        }

        // epilogue: + b' (LDS broadcast), float4 stores
        float* orow = out + ((long)(j * NBLK + blockIdx.x) * 128 + wv * 16 + r15) * 256;
#pragma unroll
        for (int ni = 0; ni < 16; ++ni) {
            f32x4 b4 = *(const f32x4*)(lds + 131072 + ni * 64 + g * 16);
            f32x4 o = acc[ni] + b4;
            *(f32x4*)(orow + ni * 16 + g * 4) = o;
        }
    }
}

extern "C" void kernel_launch(void* const* d_in, const int* in_sizes, int n_in,
                              void* d_out, int out_size, void* d_ws, size_t ws_size,
                              hipStream_t stream) {
    const float* x  = (const float*)d_in[0];
    const float* Wh = (const float*)d_in[5];
    const float* bh = (const float*)d_in[6];
    const float* gm = (const float*)d_in[7];
    float* out = (float*)d_out;
    ushort* wsW = (ushort*)d_ws;   // 128 KB

    prep_w<<<256, 256, 0, stream>>>(Wh, gm, wsW);
    ccsa_gemm<<<NBLK, 512, 0, stream>>>(x, wsW, bh, gm, out);
}

// Round 9
// 89.271 us; speedup vs baseline: 3.4322x; 3.4322x over previous
//
#include <hip/hip_runtime.h>

typedef __attribute__((ext_vector_type(8))) short bf16x8;
typedef __attribute__((ext_vector_type(4))) float f32x4;

__device__ __forceinline__ unsigned f2bf(float f) {
    union { float f; unsigned u; } v; v.f = f;
    return (v.u + 0x7FFFu + ((v.u >> 16) & 1u)) >> 16;
}

// prep: W' = gamma*Wh + I, bf16, transposed: wsW[n*256 + k]
__global__ void prep_w(const float* __restrict__ Wh, const float* __restrict__ gamma,
                       ushort* __restrict__ wsW) {
    int k = blockIdx.x, n = threadIdx.x;
    float v = gamma[0] * Wh[k * 256 + n] + (k == n ? 1.0f : 0.0f);
    wsW[n * 256 + k] = (ushort)f2bf(v);
}

// async HBM->LDS, 16 B/lane, zero VGPR footprint (lds dest wave-uniform base + lane*16)
__device__ __forceinline__ void gload16(const void* g, void* l) {
    __builtin_amdgcn_global_load_lds(
        (const __attribute__((address_space(1))) unsigned int*)g,
        (__attribute__((address_space(3))) unsigned int*)l, 16, 0, 0);
}

// out = x @ W' + gm*bh.  4096 blocks x 256 thr (4 waves), 32-row x 256-col tile.
// x tile staged fp32 into LDS via global_load_lds (source-address pre-swizzle,
// rule #21); A-frags converted fp32->bf16 at read time; B-frags from L2-resident
// W'. One barrier; latency hidden by 4 blocks/CU TLP.
__global__ __launch_bounds__(256, 4) void ccsa_gemm(
    const float* __restrict__ x, const ushort* __restrict__ wsW,
    const float* __restrict__ bh, const float* __restrict__ gamma,
    float* __restrict__ out)
{
    __shared__ char lds[32768 + 1024];   // x tile 32x256 fp32 (swz) + b' 256 f32
    const int tid  = threadIdx.x;
    const int lane = tid & 63;
    const int wv   = tid >> 6;
    const int r15  = lane & 15;
    const int g    = lane >> 4;

    const long row0 = (long)blockIdx.x * 32;
    const char* xblk = (const char*)(x + row0 * 256);

    // ---- stage x tile: wave wv stages rows wv*8..wv*8+7, one row per issue.
    // LDS linear; source col XOR-preswizzled so LDS[p] = G[p ^ ((row&7)<<4)].
#pragma unroll
    for (int i = 0; i < 8; ++i) {
        int r = wv * 8 + i;
        const char* src = xblk + r * 1024 + ((lane * 16) ^ ((r & 7) << 4));
        gload16(src, lds + r * 1024);
    }
    ((float*)(lds + 32768))[tid] = gamma[0] * bh[tid];   // b' = gm*bh

    // B fragment pointers: rows n = wv*64 + ni*16 + r15, k-offset g*8
    const ushort* bp[4];
#pragma unroll
    for (int ni = 0; ni < 4; ++ni)
        bp[ni] = wsW + (wv * 64 + ni * 16 + r15) * 256 + g * 8;

    __syncthreads();

    f32x4 acc[2][4] = {};   // [mi][ni]
    const int s = (r15 & 7) << 4;

#pragma unroll
    for (int ksl = 0; ksl < 8; ++ksl) {
        bf16x8 bc[4];
#pragma unroll
        for (int ni = 0; ni < 4; ++ni)
            bc[ni] = *(const bf16x8*)(bp[ni] + ksl * 32);

        bf16x8 af[2];
#pragma unroll
        for (int mi = 0; mi < 2; ++mi) {
            const int rb = (mi * 16 + r15) * 1024;
            const int c  = ksl * 128 + g * 32;
            f32x4 a0 = *(const f32x4*)(lds + rb + (c ^ s));
            f32x4 a1 = *(const f32x4*)(lds + rb + ((c + 16) ^ s));
            union { uint4 u; bf16x8 h; } cv;
            cv.u.x = f2bf(a0[0]) | (f2bf(a0[1]) << 16);
            cv.u.y = f2bf(a0[2]) | (f2bf(a0[3]) << 16);
            cv.u.z = f2bf(a1[0]) | (f2bf(a1[1]) << 16);
            cv.u.w = f2bf(a1[2]) | (f2bf(a1[3]) << 16);
            af[mi] = cv.h;
        }

#pragma unroll
        for (int mi = 0; mi < 2; ++mi)
#pragma unroll
            for (int ni = 0; ni < 4; ++ni)
                acc[mi][ni] = __builtin_amdgcn_mfma_f32_16x16x32_bf16(
                    bc[ni], af[mi], acc[mi][ni], 0, 0, 0);
    }

    // ---- epilogue: out = acc + b', float4 stores ----
#pragma unroll
    for (int mi = 0; mi < 2; ++mi) {
        float* orow = out + (row0 + mi * 16 + r15) * 256;
#pragma unroll
        for (int ni = 0; ni < 4; ++ni) {
            const int col = wv * 64 + ni * 16 + g * 4;
            f32x4 b4 = *(const f32x4*)(lds + 32768 + col * 4);
            f32x4 o = acc[mi][ni] + b4;
            *(f32x4*)(orow + col) = o;
        }
    }
}

extern "C" void kernel_launch(void* const* d_in, const int* in_sizes, int n_in,
                              void* d_out, int out_size, void* d_ws, size_t ws_size,
                              hipStream_t stream) {
    const float* x  = (const float*)d_in[0];
    const float* Wh = (const float*)d_in[5];
    const float* bh = (const float*)d_in[6];
    const float* gm = (const float*)d_in[7];
    float* out = (float*)d_out;
    ushort* wsW = (ushort*)d_ws;   // 128 KB

    prep_w<<<256, 256, 0, stream>>>(Wh, gm, wsW);
    ccsa_gemm<<<4096, 256, 0, stream>>>(x, wsW, bh, gm, out);
}

// Round 10
// 75.953 us; speedup vs baseline: 4.0340x; 1.1753x over previous
//
#include <hip/hip_runtime.h>
#include <hip/hip_bf16.h>

typedef __attribute__((ext_vector_type(8))) short bf16x8;
typedef __attribute__((ext_vector_type(4))) float f32x4;

__device__ __forceinline__ unsigned f2bf(float f) {
    union { float f; unsigned u; } v; v.f = f;
    return (v.u + 0x7FFFu + ((v.u >> 16) & 1u)) >> 16;
}

// prep: W' = gamma*Wh + I, bf16, transposed: wsW[n*256 + k]
__global__ void prep_w(const float* __restrict__ Wh, const float* __restrict__ gamma,
                       ushort* __restrict__ wsW) {
    int k = blockIdx.x, n = threadIdx.x;
    float v = gamma[0] * Wh[k * 256 + n] + (k == n ? 1.0f : 0.0f);
    wsW[n * 256 + k] = (ushort)f2bf(v);
}

__device__ __forceinline__ void gload16(const void* g, void* l) {
    __builtin_amdgcn_global_load_lds(
        (const __attribute__((address_space(1))) unsigned int*)g,
        (__attribute__((address_space(3))) unsigned int*)l, 16, 0, 0);
}

// fp32x8 -> bf16x8 via native cvt (compiler emits v_cvt_pk_bf16_f32)
__device__ __forceinline__ bf16x8 cvt8(f32x4 a0, f32x4 a1) {
    union { __hip_bfloat16 b[8]; bf16x8 h; } cv;
#pragma unroll
    for (int i = 0; i < 4; ++i) {
        cv.b[i]     = __float2bfloat16(a0[i]);
        cv.b[4 + i] = __float2bfloat16(a1[i]);
    }
    return cv.h;
}

// out = x @ W' + gm*bh.  2048 blocks x 512 thr (8 waves), tile 64 rows.
// Each wave owns 32 cols: its B fragments (16 x bf16x8 = 64 VGPR) are loaded
// ONCE from L2-resident W' and held in registers -> K-loop has no global
// loads and no barriers. A tile staged fp32 via global_load_lds (async, zero
// VGPR), XOR-swizzled through the source address.
__global__ __launch_bounds__(512, 4) void ccsa_gemm(
    const float* __restrict__ x, const ushort* __restrict__ wsW,
    const float* __restrict__ bh, const float* __restrict__ gamma,
    float* __restrict__ out)
{
    __shared__ char lds[65536 + 1024];   // x tile 64x256 fp32 (swz) + b'
    const int tid  = threadIdx.x;
    const int lane = tid & 63;
    const int wv   = tid >> 6;           // 0..7
    const int r15  = lane & 15;
    const int g    = lane >> 4;
    const int sw   = (r15 & 7) << 4;

    const long row0 = (long)blockIdx.x * 64;
    const char* xblk = (const char*)(x + row0 * 256);

    // ---- stage A: wave wv stages rows {i*8+wv}, one 1KB row per issue ----
#pragma unroll
    for (int i = 0; i < 8; ++i) {
        int r = i * 8 + wv;
        const char* src = xblk + r * 1024 + ((lane * 16) ^ ((r & 7) << 4));
        gload16(src, lds + r * 1024);
    }
    if (tid < 256) ((float*)(lds + 65536))[tid] = gamma[0] * bh[tid];

    // ---- B fragments: wave's 32 cols, all K -> registers, loaded once ----
    bf16x8 breg[2][8];
#pragma unroll
    for (int ni = 0; ni < 2; ++ni) {
        const ushort* bp = wsW + (wv * 32 + ni * 16 + r15) * 256 + g * 8;
#pragma unroll
        for (int ksl = 0; ksl < 8; ++ksl)
            breg[ni][ksl] = *(const bf16x8*)(bp + ksl * 32);
    }

    __syncthreads();

    f32x4 acc[4][2] = {};   // [mi][ni]

#pragma unroll
    for (int ksl = 0; ksl < 8; ++ksl) {
        const int c0 = (ksl * 128 + g * 32);
#pragma unroll
        for (int mi = 0; mi < 4; ++mi) {
            const int rb = (mi * 16 + r15) * 1024;
            f32x4 a0 = *(const f32x4*)(lds + rb + (c0 ^ sw));
            f32x4 a1 = *(const f32x4*)(lds + rb + ((c0 + 16) ^ sw));
            bf16x8 af = cvt8(a0, a1);
            acc[mi][0] = __builtin_amdgcn_mfma_f32_16x16x32_bf16(
                breg[0][ksl], af, acc[mi][0], 0, 0, 0);
            acc[mi][1] = __builtin_amdgcn_mfma_f32_16x16x32_bf16(
                breg[1][ksl], af, acc[mi][1], 0, 0, 0);
        }
    }

    // ---- epilogue: out = acc + b', float4 stores ----
#pragma unroll
    for (int mi = 0; mi < 4; ++mi) {
        float* orow = out + (row0 + mi * 16 + r15) * 256;
#pragma unroll
        for (int ni = 0; ni < 2; ++ni) {
            const int col = wv * 32 + ni * 16 + g * 4;
            f32x4 b4 = *(const f32x4*)(lds + 65536 + col * 4);
            f32x4 o = acc[mi][ni] + b4;
            *(f32x4*)(orow + col) = o;
        }
    }
}

extern "C" void kernel_launch(void* const* d_in, const int* in_sizes, int n_in,
                              void* d_out, int out_size, void* d_ws, size_t ws_size,
                              hipStream_t stream) {
    const float* x  = (const float*)d_in[0];
    const float* Wh = (const float*)d_in[5];
    const float* bh = (const float*)d_in[6];
    const float* gm = (const float*)d_in[7];
    float* out = (float*)d_out;
    ushort* wsW = (ushort*)d_ws;   // 128 KB

    prep_w<<<256, 256, 0, stream>>>(Wh, gm, wsW);
    ccsa_gemm<<<2048, 512, 0, stream>>>(x, wsW, bh, gm, out);
}